// Round 1
// 168.352 us; speedup vs baseline: 1.0060x; 1.0060x over previous
//
#include <hip/hip_runtime.h>
#include <hip/hip_bf16.h>
#include <hip/hip_fp16.h>
#include <cmath>

// Problem constants
#define BATCH   16
#define SEQ     2048
#define IN_DIM  57
#define D_MODEL 64
#define HEADDIM 32
#define D_STATE 32
#define OUT_DIM 6
#define D_INNER 128
#define NHEADS  4
#define D_CONV  4
#define D_XBC   192          // D_INNER + 2*D_STATE
#define D_XD    196          // conv channels (192) + dt (4)
#define D_IN_PROJ 324        // 2*D_INNER + 2*D_STATE + NHEADS
#define BL      (BATCH*SEQ)  // 32768

// Chunked scan config (64 chunks of 32: halves phase2 serial chain + sbuf)
#define NCHUNK  64
#define CLEN    (SEQ / NCHUNK)   // 32

// inproj tiling
#define RTILE   24
#define XPAD    60

// Workspace layout (floats). zb/xd/cb/yb/sbuf hold fp16 (2 halfs per float slot).
#define OFF_WF   ((size_t)0)
#define OFF_BF   ((size_t)18496)
#define OFF_WOC  ((size_t)18848)
#define OFF_G    ((size_t)19744)
#define OFF_P    ((size_t)21792)                    // 64*64 = 4096 floats
#define OFF_DC   ((size_t)25888)                    // BL*4 floats (cumdec per row,head)
#define OFF_ZB   ((size_t)156960)                   // BL*128 halfs = BL*64 floats
#define OFF_XD   (OFF_ZB + (size_t)BL*64)           // BL*196 halfs = BL*98 floats
#define OFF_CB   (OFF_XD + (size_t)BL*98)           // BL*32 halfs  = BL*16 floats
#define OFF_YB   (OFF_CB + (size_t)BL*16)           // BL*128 halfs = BL*64 floats
#define OFF_SB   (OFF_YB + (size_t)BL*64)           // 64*64*1024 halfs
// total ≈ 10.2M floats ≈ 41 MB

// ---------------------------------------------------------------------------
// Kernel 1: Wf = W_lin@W_in ; bf = b_lin@W_in ; W_oc = W_out@W_cls.
// Also zeroes the G accumulator using spare thread capacity.
__global__ void fuse_w_kernel(const float* __restrict__ W_lin,
                              const float* __restrict__ b_lin,
                              const float* __restrict__ W_in,
                              const float* __restrict__ W_out,
                              const float* __restrict__ W_cls,
                              float* __restrict__ Wf, float* __restrict__ bf,
                              float* __restrict__ Woc, float* __restrict__ G) {
    int idx = blockIdx.x * 256 + threadIdx.x;
    if (idx < BATCH * D_INNER) G[idx] = 0.f;
    if (idx < 58 * D_IN_PROJ) {
        int r = idx / D_IN_PROJ;
        int j = idx - r * D_IN_PROJ;
        const float* v = (r < IN_DIM) ? (W_lin + r * D_MODEL) : b_lin;
        float acc = 0.f;
#pragma unroll 8
        for (int m = 0; m < D_MODEL; ++m) acc += v[m] * W_in[m * D_IN_PROJ + j];
        if (r < IN_DIM) Wf[r * D_IN_PROJ + j] = acc;
        else            bf[j] = acc;
    } else if (idx < 58 * D_IN_PROJ + D_INNER * OUT_DIM) {
        int idx2 = idx - 58 * D_IN_PROJ;
        int i = idx2 / OUT_DIM;
        int o = idx2 - i * OUT_DIM;
        float acc = 0.f;
#pragma unroll 8
        for (int j = 0; j < D_MODEL; ++j)
            acc += W_out[i * D_MODEL + j] * W_cls[j * OUT_DIM + o];
        Woc[i * OUT_DIM + o] = acc;
    }
}

// ---------------------------------------------------------------------------
// Kernel 2: LDS-staged in-projection. Block: 24 rows x 324 cols.
// Outputs quantized to fp16: z cols (0..127) -> zbh (stride 128 halfs),
// conv-in + dt cols -> xdh (stride 196 halfs).
__global__ __launch_bounds__(256) void inproj_kernel(
        const float* __restrict__ x,
        const float* __restrict__ Wf,
        const float* __restrict__ bf,
        __half* __restrict__ zbh,
        __half* __restrict__ xdh) {
    __shared__ float xs[RTILE][XPAD];
    int r0 = blockIdx.x * RTILE;
    for (int i = threadIdx.x; i < RTILE * IN_DIM; i += 256) {
        size_t g = (size_t)r0 * IN_DIM + i;
        float v = (g < (size_t)BL * IN_DIM) ? x[g] : 0.f;
        xs[i / IN_DIM][i % IN_DIM] = v;
    }
    __syncthreads();
    if (threadIdx.x >= 243) return;
    int rset = threadIdx.x / 81;
    int cg   = threadIdx.x - rset * 81;
    int j0   = cg * 4;
    float4 bias = *(const float4*)(bf + j0);
    float4 acc[8];
#pragma unroll
    for (int r = 0; r < 8; ++r) acc[r] = bias;
    const float* w = Wf + j0;
    const float* xrow = &xs[rset * 8][0];
#pragma unroll 2
    for (int kc = 0; kc < 14; ++kc) {
        int k = kc * 4;
        float4 wv0 = *(const float4*)(w + (size_t)(k + 0) * D_IN_PROJ);
        float4 wv1 = *(const float4*)(w + (size_t)(k + 1) * D_IN_PROJ);
        float4 wv2 = *(const float4*)(w + (size_t)(k + 2) * D_IN_PROJ);
        float4 wv3 = *(const float4*)(w + (size_t)(k + 3) * D_IN_PROJ);
#pragma unroll
        for (int r = 0; r < 8; ++r) {
            float4 xv = *(const float4*)(xrow + r * XPAD + k);
            acc[r].x += xv.x * wv0.x + xv.y * wv1.x + xv.z * wv2.x + xv.w * wv3.x;
            acc[r].y += xv.x * wv0.y + xv.y * wv1.y + xv.z * wv2.y + xv.w * wv3.y;
            acc[r].z += xv.x * wv0.z + xv.y * wv1.z + xv.z * wv2.z + xv.w * wv3.z;
            acc[r].w += xv.x * wv0.w + xv.y * wv1.w + xv.z * wv2.w + xv.w * wv3.w;
        }
    }
    {
        float4 wv = *(const float4*)(w + (size_t)56 * D_IN_PROJ);
#pragma unroll
        for (int r = 0; r < 8; ++r) {
            float xv = xrow[r * XPAD + 56];
            acc[r].x += xv * wv.x; acc[r].y += xv * wv.y;
            acc[r].z += xv * wv.z; acc[r].w += xv * wv.w;
        }
    }
#pragma unroll
    for (int r = 0; r < 8; ++r) {
        int row = r0 + rset * 8 + r;
        if (row < BL) {
            __half2 h01 = __floats2half2_rn(acc[r].x, acc[r].y);
            __half2 h23 = __floats2half2_rn(acc[r].z, acc[r].w);
            uint2 u;
            u.x = *(unsigned*)&h01;
            u.y = *(unsigned*)&h23;
            if (j0 < D_INNER)
                *(uint2*)(zbh + (size_t)row * D_INNER + j0) = u;
            else
                *(uint2*)(xdh + (size_t)row * D_XD + (j0 - D_INNER)) = u;
        }
    }
}

// ---------------------------------------------------------------------------
// Conv + dt prologue (fp16 xd input, fp32 compute). CLEN=32 aware.
__device__ __forceinline__ void conv_prologue(
        const __half* __restrict__ xdh,
        const float* __restrict__ conv_w, const float* __restrict__ conv_b,
        const float* __restrict__ dt_bias, const float* __restrict__ A_log,
        size_t rbase, int c, int tid,
        float (*xbt)[D_XBC], float (*ddl)[8]) {
    if (tid < D_XBC) {
        int ch = tid;
        float w0 = conv_w[ch*4+0], w1 = conv_w[ch*4+1];
        float w2 = conv_w[ch*4+2], w3 = conv_w[ch*4+3];
        float cb = conv_b[ch];
        const __half* src = xdh + rbase * D_XD + ch;
        float vm1 = 0.f, vm2 = 0.f, vm3 = 0.f;
        if (c > 0) {
            vm1 = __half2float(src[-(int)D_XD]);
            vm2 = __half2float(src[-2*(int)D_XD]);
            vm3 = __half2float(src[-3*(int)D_XD]);
        }
#pragma unroll
        for (int i = 0; i < CLEN; ++i) {
            float v0 = __half2float(src[(size_t)i * D_XD]);
            float a = cb + v0 * w3 + vm1 * w2 + vm2 * w1 + vm3 * w0;
            xbt[i][ch] = a / (1.f + expf(-a));   // SiLU
            vm3 = vm2; vm2 = vm1; vm1 = v0;
        }
    } else {
        int idx = tid - D_XBC;       // 0..63
        int h = idx >> 4;
        int i0 = idx & 15;
        float db = dt_bias[h];
        float nA = -expf(A_log[h]);
#pragma unroll
        for (int i = i0; i < CLEN; i += 16) {
            float v = __half2float(xdh[(rbase + i) * D_XD + 192 + h]) + db;
            float dtv = (v > 20.f) ? v : log1pf(expf(v));
            ddl[i][h * 2]     = dtv;
            ddl[i][h * 2 + 1] = expf(dtv * nA);
        }
    }
}

// ---------------------------------------------------------------------------
// Phase 1: conv once -> UNSEEDED scan with fused C-dot -> writes:
//   y_u (fp16, includes D*x), C rows (fp16), cumdec (fp32),
//   chunk-final state (fp16 sbuf), chunk decay product (Pbuf).
// Seeded outputs are reconstructed in phase3 as y = y_u + cumdec*(C·seed).
__global__ __launch_bounds__(256) void scan_phase1_kernel(
        const __half* __restrict__ xdh,
        const float* __restrict__ conv_w, const float* __restrict__ conv_b,
        const float* __restrict__ dt_bias, const float* __restrict__ A_log,
        const float* __restrict__ Dp,
        __half* __restrict__ sbuf, float* __restrict__ Pbuf,
        __half* __restrict__ ybuf, __half* __restrict__ Cbuf,
        float* __restrict__ Dcum) {
    int b = blockIdx.x >> 6;          // NCHUNK=64
    int c = blockIdx.x & (NCHUNK - 1);
    int tid = threadIdx.x;
    __shared__ float xbt[CLEN][D_XBC];     // 24 KB conv outputs
    __shared__ float ddl[CLEN][8];         // 1 KB {dt,dec}x4
    __shared__ __half yl[CLEN][D_INNER];   // 8 KB y_u staging
    __shared__ float dcl[CLEN * 4];        // 0.5 KB cumdec staging
    size_t rbase = (size_t)b * SEQ + (size_t)c * CLEN;
    conv_prologue(xdh, conv_w, conv_b, dt_bias, A_log, rbase, c, tid, xbt, ddl);
    __syncthreads();
    int h = tid >> 6, lane = tid & 63;
    int p = lane >> 1, n0 = (lane & 1) * 16;
    float Dh = Dp[h];
    float4 s0 = make_float4(0.f,0.f,0.f,0.f), s1 = s0, s2 = s0, s3 = s0;
    float pacc = 1.f;
#pragma unroll 4
    for (int i = 0; i < CLEN; ++i) {
        float dtv = ddl[i][h * 2];
        float dec = ddl[i][h * 2 + 1];
        float xv = xbt[i][h * HEADDIM + p];
        const float* Bp = &xbt[i][D_INNER + n0];
        const float* Cp = &xbt[i][D_INNER + D_STATE + n0];
        float4 B0 = *(const float4*)(Bp + 0);
        float4 B1 = *(const float4*)(Bp + 4);
        float4 B2 = *(const float4*)(Bp + 8);
        float4 B3 = *(const float4*)(Bp + 12);
        float4 C0 = *(const float4*)(Cp + 0);
        float4 C1 = *(const float4*)(Cp + 4);
        float4 C2 = *(const float4*)(Cp + 8);
        float4 C3 = *(const float4*)(Cp + 12);
        float coef = dtv * xv;
        s0.x = s0.x*dec + coef*B0.x; s0.y = s0.y*dec + coef*B0.y;
        s0.z = s0.z*dec + coef*B0.z; s0.w = s0.w*dec + coef*B0.w;
        s1.x = s1.x*dec + coef*B1.x; s1.y = s1.y*dec + coef*B1.y;
        s1.z = s1.z*dec + coef*B1.z; s1.w = s1.w*dec + coef*B1.w;
        s2.x = s2.x*dec + coef*B2.x; s2.y = s2.y*dec + coef*B2.y;
        s2.z = s2.z*dec + coef*B2.z; s2.w = s2.w*dec + coef*B2.w;
        s3.x = s3.x*dec + coef*B3.x; s3.y = s3.y*dec + coef*B3.y;
        s3.z = s3.z*dec + coef*B3.z; s3.w = s3.w*dec + coef*B3.w;
        pacc *= dec;
        float part = s0.x*C0.x + s0.y*C0.y + s0.z*C0.z + s0.w*C0.w
                   + s1.x*C1.x + s1.y*C1.y + s1.z*C1.z + s1.w*C1.w
                   + s2.x*C2.x + s2.y*C2.y + s2.z*C2.z + s2.w*C2.w
                   + s3.x*C3.x + s3.y*C3.y + s3.z*C3.z + s3.w*C3.w;
        part += __shfl_xor(part, 1);
        if (lane == 0) dcl[i * 4 + h] = pacc;
        if ((lane & 1) == 0)
            yl[i][h * HEADDIM + p] = __float2half(part + Dh * xv);
    }
    int bh = b * NHEADS + h;
    __half2 hs[8];
    hs[0] = __floats2half2_rn(s0.x, s0.y); hs[1] = __floats2half2_rn(s0.z, s0.w);
    hs[2] = __floats2half2_rn(s1.x, s1.y); hs[3] = __floats2half2_rn(s1.z, s1.w);
    hs[4] = __floats2half2_rn(s2.x, s2.y); hs[5] = __floats2half2_rn(s2.z, s2.w);
    hs[6] = __floats2half2_rn(s3.x, s3.y); hs[7] = __floats2half2_rn(s3.z, s3.w);
    uint4* sp = (uint4*)(sbuf + ((size_t)bh * NCHUNK + c) * 1024) + lane * 2;
    sp[0] = *(uint4*)&hs[0];
    sp[1] = *(uint4*)&hs[4];
    if (lane == 0) Pbuf[bh * NCHUNK + c] = pacc;
    __syncthreads();
    // y_u out: CLEN*128 halfs = 512 uint4, coalesced
    {
        const uint4* ysrc = (const uint4*)&yl[0][0];
        uint4* ydst = (uint4*)(ybuf + rbase * D_INNER);
        ydst[tid]       = ysrc[tid];
        ydst[tid + 256] = ysrc[tid + 256];
    }
    // C out: CLEN*32 halfs = 512 half2
    for (int idx = tid; idx < CLEN * 16; idx += 256) {
        int r  = idx >> 4;
        int n2 = (idx & 15) * 2;
        __half2 hv = __floats2half2_rn(xbt[r][D_INNER + D_STATE + n2],
                                       xbt[r][D_INNER + D_STATE + n2 + 1]);
        *((__half2*)(Cbuf + (rbase + r) * D_STATE + n2)) = hv;
    }
    // cumdec out: CLEN*4 floats
    if (tid < CLEN * 4) Dcum[rbase * 4 + tid] = dcl[tid];
}

// ---------------------------------------------------------------------------
// Phase 2: combine fp16 chunk states (64-long serial chain, was 128).
// Stores the EXCLUSIVE prefix (seed for chunk c) back in place.
__global__ __launch_bounds__(256) void scan_phase2_kernel(
        __half* __restrict__ sbuf, const float* __restrict__ Pbuf) {
    int bh = blockIdx.x >> 1;
    int q  = blockIdx.x & 1;
    int idx = q * 256 + threadIdx.x;     // 0..511
    unsigned* s32 = (unsigned*)sbuf;
    float rx = 0.f, ry = 0.f;
#pragma unroll 8
    for (int c = 0; c < NCHUNK; ++c) {
        size_t a = ((size_t)bh * NCHUNK + c) * 512 + idx;
        unsigned v = s32[a];
        float Pv = Pbuf[bh * NCHUNK + c];
        __half2 hv = *(__half2*)&v;
        float2 t = __half22float2(hv);
        __half2 hr = __floats2half2_rn(rx, ry);
        s32[a] = *(unsigned*)&hr;
        rx = rx * Pv + t.x;
        ry = ry * Pv + t.y;
    }
}

// ---------------------------------------------------------------------------
// Phase 3 (lite): y = y_u + cumdec*(C·seed), then gate*silu(z) + RMSNorm + G.
// No conv, no recurrence, no xdh read.
__global__ __launch_bounds__(256) void scan_phase3_kernel(
        const __half* __restrict__ ybuf, const __half* __restrict__ Cbuf,
        const float* __restrict__ Dcum, const __half* __restrict__ zbh,
        const __half* __restrict__ sbuf, const float* __restrict__ norm_w,
        float* __restrict__ G) {
    int b = blockIdx.x >> 6;          // NCHUNK=64
    int c = blockIdx.x & (NCHUNK - 1);
    int tid = threadIdx.x;
    __shared__ float ylds[CLEN][D_INNER];   // 16 KB
    __shared__ float dcl[CLEN * 4];         // 0.5 KB
    __shared__ float red[4][D_INNER];       // 2 KB
    size_t rbase = (size_t)b * SEQ + (size_t)c * CLEN;
    int h = tid >> 6, lane = tid & 63;
    int p = lane >> 1, n0 = (lane & 1) * 16;
    int bh = b * NHEADS + h;
    // seed load first (long-latency global, overlaps ybuf staging)
    const uint4* sp = (const uint4*)(sbuf + ((size_t)bh * NCHUNK + c) * 1024) + lane * 2;
    uint4 u0 = sp[0], u1 = sp[1];
    // stage y_u -> fp32 LDS (coalesced half2)
    {
        const __half2* ysrc = (const __half2*)(ybuf + rbase * D_INNER);
        for (int idx = tid; idx < CLEN * D_INNER / 2; idx += 256) {
            float2 f = __half22float2(ysrc[idx]);
            int r  = idx >> 6;
            int c2 = (idx & 63) * 2;
            ylds[r][c2]     = f.x;
            ylds[r][c2 + 1] = f.y;
        }
    }
    if (tid < CLEN * 4) dcl[tid] = Dcum[rbase * 4 + tid];
    // unpack fp16 seed -> fp32 regs (state dims n0..n0+15 for row p)
    float4 s0, s1, s2, s3;
    {
        const __half2* hp0 = (const __half2*)&u0;
        const __half2* hp1 = (const __half2*)&u1;
        float2 f;
        f = __half22float2(hp0[0]); s0.x = f.x; s0.y = f.y;
        f = __half22float2(hp0[1]); s0.z = f.x; s0.w = f.y;
        f = __half22float2(hp0[2]); s1.x = f.x; s1.y = f.y;
        f = __half22float2(hp0[3]); s1.z = f.x; s1.w = f.y;
        f = __half22float2(hp1[0]); s2.x = f.x; s2.y = f.y;
        f = __half22float2(hp1[1]); s2.z = f.x; s2.w = f.y;
        f = __half22float2(hp1[2]); s3.x = f.x; s3.y = f.y;
        f = __half22float2(hp1[3]); s3.z = f.x; s3.w = f.y;
    }
    __syncthreads();
#pragma unroll 4
    for (int i = 0; i < CLEN; ++i) {
        const uint4* cp = (const uint4*)(Cbuf + (rbase + i) * D_STATE + n0);
        uint4 ca = cp[0], cb = cp[1];
        const __half2* cha = (const __half2*)&ca;
        const __half2* chb = (const __half2*)&cb;
        float2 f0 = __half22float2(cha[0]);
        float2 f1 = __half22float2(cha[1]);
        float2 f2 = __half22float2(cha[2]);
        float2 f3 = __half22float2(cha[3]);
        float2 f4 = __half22float2(chb[0]);
        float2 f5 = __half22float2(chb[1]);
        float2 f6 = __half22float2(chb[2]);
        float2 f7 = __half22float2(chb[3]);
        float part = s0.x*f0.x + s0.y*f0.y + s0.z*f1.x + s0.w*f1.y
                   + s1.x*f2.x + s1.y*f2.y + s1.z*f3.x + s1.w*f3.y
                   + s2.x*f4.x + s2.y*f4.y + s2.z*f5.x + s2.w*f5.y
                   + s3.x*f6.x + s3.y*f6.y + s3.z*f7.x + s3.w*f7.y;
        part += __shfl_xor(part, 1);
        if ((lane & 1) == 0)
            ylds[i][h * HEADDIM + p] += dcl[i * 4 + h] * part;
    }
    __syncthreads();
    // gate + RMSNorm from LDS; wave h handles rows r = h, h+4, ...
    float acc0 = 0.f, acc1 = 0.f;
    for (int r = h; r < CLEN; r += 4) {
        size_t bl = rbase + r;
        float2 yv = *(const float2*)(&ylds[r][lane * 2]);
        float2 zv = __half22float2(*((const __half2*)(zbh + bl * D_INNER) + lane));
        float g0 = yv.x * (zv.x / (1.f + expf(-zv.x)));
        float g1 = yv.y * (zv.y / (1.f + expf(-zv.y)));
        float sq = g0 * g0 + g1 * g1;
#pragma unroll
        for (int m = 1; m < 64; m <<= 1) sq += __shfl_xor(sq, m);
        float rms = 1.0f / sqrtf(sq * (1.f / 128.f) + 1e-5f);
        acc0 += g0 * rms;
        acc1 += g1 * rms;
    }
    red[h][lane * 2]     = acc0;
    red[h][lane * 2 + 1] = acc1;
    __syncthreads();
    if (tid < D_INNER) {
        float sg = red[0][tid] + red[1][tid] + red[2][tid] + red[3][tid];
        atomicAdd(&G[b * D_INNER + tid], sg * norm_w[tid]);
    }
}

// ---------------------------------------------------------------------------
// Kernel 6: out[b][o] = b_cls[o] + (G[b] @ W_oc)[o] / SEQ
__global__ void head_kernel(const float* __restrict__ G,
                            const float* __restrict__ Woc,
                            const float* __restrict__ b_cls,
                            float* __restrict__ out) {
    int tid = threadIdx.x;
    if (tid >= BATCH * OUT_DIM) return;
    int b = tid / OUT_DIM, o = tid - b * OUT_DIM;
    float acc = 0.f;
#pragma unroll 8
    for (int i = 0; i < D_INNER; ++i)
        acc += G[b * D_INNER + i] * Woc[i * OUT_DIM + o];
    out[b * OUT_DIM + o] = acc * (1.f / (float)SEQ) + b_cls[o];
}

// ---------------------------------------------------------------------------
extern "C" void kernel_launch(void* const* d_in, const int* in_sizes, int n_in,
                              void* d_out, int out_size, void* d_ws, size_t ws_size,
                              hipStream_t stream) {
    const float* x       = (const float*)d_in[0];
    const float* W_lin   = (const float*)d_in[1];
    const float* b_lin   = (const float*)d_in[2];
    const float* W_in    = (const float*)d_in[3];
    const float* conv_w  = (const float*)d_in[4];
    const float* conv_b  = (const float*)d_in[5];
    const float* dt_bias = (const float*)d_in[6];
    const float* A_log   = (const float*)d_in[7];
    const float* Dp      = (const float*)d_in[8];
    const float* norm_w  = (const float*)d_in[9];
    const float* W_out   = (const float*)d_in[10];
    const float* W_cls   = (const float*)d_in[11];
    const float* b_cls   = (const float*)d_in[12];
    float* out = (float*)d_out;

    float* ws = (float*)d_ws;
    float* Wf    = ws + OFF_WF;
    float* bf    = ws + OFF_BF;
    float* Woc   = ws + OFF_WOC;
    float* G     = ws + OFF_G;
    float* Pbuf  = ws + OFF_P;
    float* Dcum  = ws + OFF_DC;
    __half* zbh  = (__half*)(ws + OFF_ZB);
    __half* xdh  = (__half*)(ws + OFF_XD);
    __half* Cbh  = (__half*)(ws + OFF_CB);
    __half* ybh  = (__half*)(ws + OFF_YB);
    __half* sbuf = (__half*)(ws + OFF_SB);

    // 1) fused weight precompute (also zeroes G — no separate memset)
    fuse_w_kernel<<<(58 * D_IN_PROJ + D_INNER * OUT_DIM + 255) / 256, 256, 0, stream>>>(
        W_lin, b_lin, W_in, W_out, W_cls, Wf, bf, Woc, G);

    // 2) in-projection (LDS-staged, 24 rows/block; fp16 z / xd outputs)
    inproj_kernel<<<(BL + RTILE - 1) / RTILE, 256, 0, stream>>>(x, Wf, bf, zbh, xdh);

    // 3) chunked selective scan: conv+recurrence ONCE (phase1), seed combine
    //    (phase2, 64-chain), then cheap output-correction+gating (phase3).
    scan_phase1_kernel<<<BATCH * NCHUNK, 256, 0, stream>>>(
        xdh, conv_w, conv_b, dt_bias, A_log, Dp, sbuf, Pbuf, ybh, Cbh, Dcum);
    scan_phase2_kernel<<<64 * 2, 256, 0, stream>>>(sbuf, Pbuf);
    scan_phase3_kernel<<<BATCH * NCHUNK, 256, 0, stream>>>(
        ybh, Cbh, Dcum, zbh, sbuf, norm_w, G);

    // 4) classifier head
    head_kernel<<<1, 128, 0, stream>>>(G, Woc, b_cls, out);
}